// Round 5
// baseline (150.437 us; speedup 1.0000x reference)
//
#include <hip/hip_runtime.h>
#include <hip/hip_fp16.h>

#define GNN_IN 128
#define HID 256

typedef _Float16 f16x2 __attribute__((ext_vector_type(2)));
struct __align__(8) h4v { f16x2 a, b; };  // 4 fp16

__device__ __forceinline__ float fdot2f(f16x2 a, f16x2 b, float c) {
#if __has_builtin(__builtin_amdgcn_fdot2)
    return __builtin_amdgcn_fdot2(a, b, c, false);
#else
    return fmaf((float)a.x, (float)b.x, fmaf((float)a.y, (float)b.y, c));
#endif
}

__device__ __forceinline__ f16x2 pkcvt(float x, float y) {
#if __has_builtin(__builtin_amdgcn_cvt_pkrtz)
    return __builtin_bit_cast(f16x2, __builtin_amdgcn_cvt_pkrtz(x, y));
#else
    f16x2 r; r.x = (_Float16)x; r.y = (_Float16)y; return r;
#endif
}

// ---------------------------------------------------------------------------
// Detect int64 vs int32 edge_index (int64 little-endian high words are 0).
// ---------------------------------------------------------------------------
__global__ void detect_kernel(const unsigned int* __restrict__ ei,
                              unsigned int* __restrict__ flag) {
    if (threadIdx.x == 0 && blockIdx.x == 0) {
        unsigned int v = 0;
        for (int i = 1; i < 256; i += 2) v |= ei[i];
        *flag = (v == 0u) ? 1u : 0u;
    }
}

// ---------------------------------------------------------------------------
// Phase 1: [A|B] = x @ [w1_top | w1_bot]  -> fp16, LDS-free.
// Block: 16 node-rows x 256 cols. x-tile rows are block-uniform -> scalar
// loads (SGPRs); each thread owns one output column; zero ds_read.
// ---------------------------------------------------------------------------
__global__ void __launch_bounds__(256) node_gemm_kernel(
    const float* __restrict__ x, const float* __restrict__ w1,
    __half* __restrict__ AB, int num_nodes) {
    const int tid = threadIdx.x;
    const int r0  = blockIdx.x * 16;
    const float* __restrict__ w = w1 + (size_t)blockIdx.y * GNN_IN * HID + tid;

    float acc[16];
#pragma unroll
    for (int r = 0; r < 16; ++r) acc[r] = 0.f;

    for (int k0 = 0; k0 < GNN_IN; k0 += 4) {
        float4 xv[16];
#pragma unroll
        for (int r = 0; r < 16; ++r) {
            const int rr = min(r0 + r, num_nodes - 1);  // uniform, SALU
            xv[r] = *(const float4*)(x + (size_t)rr * GNN_IN + k0);
        }
        const float wv0 = w[(size_t)(k0 + 0) * HID];
        const float wv1 = w[(size_t)(k0 + 1) * HID];
        const float wv2 = w[(size_t)(k0 + 2) * HID];
        const float wv3 = w[(size_t)(k0 + 3) * HID];
#pragma unroll
        for (int r = 0; r < 16; ++r) {
            acc[r] = fmaf(xv[r].x, wv0, acc[r]);
            acc[r] = fmaf(xv[r].y, wv1, acc[r]);
            acc[r] = fmaf(xv[r].z, wv2, acc[r]);
            acc[r] = fmaf(xv[r].w, wv3, acc[r]);
        }
    }
    __half* ob = AB + (size_t)blockIdx.y * num_nodes * HID + tid;
#pragma unroll
    for (int r = 0; r < 16; ++r)
        if (r0 + r < num_nodes) ob[(size_t)(r0 + r) * HID] = __float2half_rn(acc[r]);
}

// ---------------------------------------------------------------------------
// Phase 2: wave per edge, 2 edges/iter. Edge id is wave-uniform ->
// readfirstlane -> index/ed via scalar loads, gathers via SGPR-base + lane
// offset. Packed fp16 h-math, v_dot2_f32_f16 accumulate (fp32).
// ---------------------------------------------------------------------------
__global__ void __launch_bounds__(256) edge_kernel_fp16(
    const __half* __restrict__ A, const __half* __restrict__ B,
    const void* __restrict__ ei, const float* __restrict__ ed,
    const float* __restrict__ w1, const float* __restrict__ b1,
    const float* __restrict__ w2, const float* __restrict__ b2,
    const unsigned int* __restrict__ flag,
    float* __restrict__ out, int num_edges) {
    const int lane   = threadIdx.x & 63;
    const int wave   = (blockIdx.x * blockDim.x + threadIdx.x) >> 6;
    const int nwaves = (gridDim.x * blockDim.x) >> 6;
    const int c0     = lane << 2;  // 4 columns per lane

    const float4 b1v = *(const float4*)(b1 + c0);
    float wt[4][4];
#pragma unroll
    for (int k = 0; k < 4; ++k)
        *(float4*)wt[k] = *(const float4*)(w1 + (size_t)(2 * GNN_IN + k) * HID + c0);
    const float4 w2f = *(const float4*)(w2 + c0);
    const f16x2  w2A = pkcvt(w2f.x, w2f.y);
    const f16x2  w2B = pkcvt(w2f.z, w2f.w);
    const float  b2v = b2[0];
    const int   is64 = __builtin_amdgcn_readfirstlane((int)(*flag));
    const f16x2 zero = {(_Float16)0.f, (_Float16)0.f};

    const int chunk = (num_edges + nwaves - 1) / nwaves;
    const int e0s = __builtin_amdgcn_readfirstlane(wave * chunk);
    const int e1s = __builtin_amdgcn_readfirstlane(min(num_edges, wave * chunk + chunk));

    for (int es = e0s; es < e1s; es += 2) {
        const int ebs = (es + 1 < e1s) ? (es + 1) : es;  // duplicate on tail
        int r0i, c0i, r1i, c1i;
        if (is64) {
            const int4 v0 = *(const int4*)((const char*)ei + (size_t)es * 16);
            const int4 v1 = *(const int4*)((const char*)ei + (size_t)ebs * 16);
            r0i = v0.x; c0i = v0.z; r1i = v1.x; c1i = v1.z;
        } else {
            const int2 v0 = *(const int2*)((const char*)ei + (size_t)es * 8);
            const int2 v1 = *(const int2*)((const char*)ei + (size_t)ebs * 8);
            r0i = v0.x; c0i = v0.y; r1i = v1.x; c1i = v1.y;
        }
        // gathers: SGPR base + (lane<<3) byte offset
        const h4v a0  = *(const h4v*)(A + (size_t)r0i * HID + c0);
        const h4v bb0 = *(const h4v*)(B + (size_t)c0i * HID + c0);
        const h4v a1  = *(const h4v*)(A + (size_t)r1i * HID + c0);
        const h4v bb1 = *(const h4v*)(B + (size_t)c1i * HID + c0);
        const float4 ed0 = *(const float4*)(ed + (size_t)es * 4);
        const float4 ed1 = *(const float4*)(ed + (size_t)ebs * 4);

        float p0 = 0.f, p1 = 0.f;
        {
            float c_[4] = {b1v.x, b1v.y, b1v.z, b1v.w};
            const float ep[4] = {ed0.x, ed0.y, ed0.z, ed0.w};
#pragma unroll
            for (int k = 0; k < 4; ++k)
#pragma unroll
                for (int j = 0; j < 4; ++j) c_[j] = fmaf(ep[k], wt[k][j], c_[j]);
            f16x2 h0 = (a0.a + bb0.a) + pkcvt(c_[0], c_[1]);
            f16x2 h1 = (a0.b + bb0.b) + pkcvt(c_[2], c_[3]);
            h0 = __builtin_elementwise_max(h0, zero);
            h1 = __builtin_elementwise_max(h1, zero);
            p0 = fdot2f(h0, w2A, fdot2f(h1, w2B, p0));
        }
        {
            float c_[4] = {b1v.x, b1v.y, b1v.z, b1v.w};
            const float ep[4] = {ed1.x, ed1.y, ed1.z, ed1.w};
#pragma unroll
            for (int k = 0; k < 4; ++k)
#pragma unroll
                for (int j = 0; j < 4; ++j) c_[j] = fmaf(ep[k], wt[k][j], c_[j]);
            f16x2 h0 = (a1.a + bb1.a) + pkcvt(c_[0], c_[1]);
            f16x2 h1 = (a1.b + bb1.b) + pkcvt(c_[2], c_[3]);
            h0 = __builtin_elementwise_max(h0, zero);
            h1 = __builtin_elementwise_max(h1, zero);
            p1 = fdot2f(h0, w2A, fdot2f(h1, w2B, p1));
        }
#pragma unroll
        for (int off = 32; off >= 1; off >>= 1) {
            p0 += __shfl_xor(p0, off, 64);
            p1 += __shfl_xor(p1, off, 64);
        }
        const float s0 = 1.f / (1.f + __expf(-(p0 + b2v)));
        const float s1 = 1.f / (1.f + __expf(-(p1 + b2v)));
        if (lane == 0) {
            out[es] = s0;
            if (ebs != es) out[ebs] = s1;
        }
    }
}

// ---------------------------------------------------------------------------
// Fallback (ws too small): direct per-edge computation, fp32.
// ---------------------------------------------------------------------------
__global__ void __launch_bounds__(256) edge_direct_kernel(
    const float* __restrict__ x, const void* __restrict__ ei,
    const float* __restrict__ ed, const float* __restrict__ w1,
    const float* __restrict__ b1, const float* __restrict__ w2,
    const float* __restrict__ b2, const unsigned int* __restrict__ flag,
    float* __restrict__ out, int num_edges, int num_nodes) {
    const int lane   = threadIdx.x & 63;
    const int wave   = (blockIdx.x * blockDim.x + threadIdx.x) >> 6;
    const int nwaves = (gridDim.x * blockDim.x) >> 6;
    const int c0     = lane << 2;

    const float4 w2v = *(const float4*)(w2 + c0);
    const float4 b1v = *(const float4*)(b1 + c0);
    float wt[4][4];
#pragma unroll
    for (int k = 0; k < 4; ++k)
        *(float4*)wt[k] = *(const float4*)(w1 + (size_t)(2 * GNN_IN + k) * HID + c0);
    const float b2v  = b2[0];
    const int   is64 = flag ? (int)(*flag) : 0;

    const float* w2p = (const float*)&w2v;
    const float* b1p = (const float*)&b1v;

    const int chunk = (num_edges + nwaves - 1) / nwaves;
    const int e0 = wave * chunk;
    const int e1 = min(num_edges, e0 + chunk);

    for (int e = e0; e < e1; ++e) {
        int row, col;
        if (is64) {
            const int4 v = ((const int4*)ei)[e];
            row = v.x; col = v.z;
        } else {
            const int2 v = ((const int2*)ei)[e];
            row = v.x; col = v.y;
        }
        row = min(max(row, 0), num_nodes - 1);
        col = min(max(col, 0), num_nodes - 1);

        const float4 edv = *(const float4*)(ed + (size_t)e * 4);
        const float* edp = (const float*)&edv;

        float h4[4];
#pragma unroll
        for (int jj = 0; jj < 4; ++jj) {
            float h = b1p[jj];
#pragma unroll
            for (int k = 0; k < 4; ++k) h = fmaf(edp[k], wt[k][jj], h);
            h4[jj] = h;
        }
        const float* xr = x + (size_t)row * GNN_IN;
        const float* xc = x + (size_t)col * GNN_IN;
        for (int k = 0; k < GNN_IN; ++k) {
            const float xv = xr[k];
            const float4 wv = *(const float4*)(w1 + (size_t)k * HID + c0);
            h4[0] = fmaf(xv, wv.x, h4[0]); h4[1] = fmaf(xv, wv.y, h4[1]);
            h4[2] = fmaf(xv, wv.z, h4[2]); h4[3] = fmaf(xv, wv.w, h4[3]);
        }
        for (int k = 0; k < GNN_IN; ++k) {
            const float xv = xc[k];
            const float4 wv = *(const float4*)(w1 + (size_t)(GNN_IN + k) * HID + c0);
            h4[0] = fmaf(xv, wv.x, h4[0]); h4[1] = fmaf(xv, wv.y, h4[1]);
            h4[2] = fmaf(xv, wv.z, h4[2]); h4[3] = fmaf(xv, wv.w, h4[3]);
        }
        float p = 0.f;
#pragma unroll
        for (int jj = 0; jj < 4; ++jj) {
            const float h = fmaxf(h4[jj], 0.f);
            p = fmaf(h, w2p[jj], p);
        }
#pragma unroll
        for (int off = 32; off >= 1; off >>= 1) p += __shfl_xor(p, off, 64);
        if (lane == 0) out[e] = 1.f / (1.f + __expf(-(p + b2v)));
    }
}

extern "C" void kernel_launch(void* const* d_in, const int* in_sizes, int n_in,
                              void* d_out, int out_size, void* d_ws, size_t ws_size,
                              hipStream_t stream) {
    const float* x  = (const float*)d_in[0];
    const void*  ei = d_in[1];
    const float* ed = (const float*)d_in[2];
    const float* w1 = (const float*)d_in[3];
    const float* b1 = (const float*)d_in[4];
    const float* w2 = (const float*)d_in[5];
    const float* b2 = (const float*)d_in[6];
    float* out = (float*)d_out;

    const int num_nodes = in_sizes[0] / GNN_IN;  // 10000
    const int num_edges = in_sizes[1] / 2;       // 640000

    unsigned int* flag = nullptr;
    if (ws_size >= 16) {
        flag = (unsigned int*)d_ws;
        detect_kernel<<<1, 64, 0, stream>>>((const unsigned int*)ei, flag);
    }

    const size_t need = 256 + (size_t)2 * num_nodes * HID * sizeof(__half);
    if (flag && ws_size >= need) {
        __half* A = (__half*)((char*)d_ws + 256);
        node_gemm_kernel<<<dim3((num_nodes + 15) / 16, 2), 256, 0, stream>>>(
            x, w1, A, num_nodes);
        __half* Bp = A + (size_t)num_nodes * HID;
        edge_kernel_fp16<<<2048, 256, 0, stream>>>(A, Bp, ei, ed, w1, b1, w2, b2,
                                                   flag, out, num_edges);
    } else {
        edge_direct_kernel<<<4096, 256, 0, stream>>>(x, ei, ed, w1, b1, w2, b2,
                                                     flag, out, num_edges, num_nodes);
    }
}

// Round 6
// 114.269 us; speedup vs baseline: 1.3165x; 1.3165x over previous
//
#include <hip/hip_runtime.h>
#include <hip/hip_fp16.h>

#define GNN_IN 128
#define HID 256

typedef _Float16 f16x2 __attribute__((ext_vector_type(2)));
struct __align__(8) h4v { f16x2 a, b; };  // 4 fp16

__device__ __forceinline__ float fdot2f(f16x2 a, f16x2 b, float c) {
#if __has_builtin(__builtin_amdgcn_fdot2)
    return __builtin_amdgcn_fdot2(a, b, c, false);
#else
    return fmaf((float)a.x, (float)b.x, fmaf((float)a.y, (float)b.y, c));
#endif
}

__device__ __forceinline__ f16x2 pkcvt(float x, float y) {
#if __has_builtin(__builtin_amdgcn_cvt_pkrtz)
    return __builtin_bit_cast(f16x2, __builtin_amdgcn_cvt_pkrtz(x, y));
#else
    f16x2 r; r.x = (_Float16)x; r.y = (_Float16)y; return r;
#endif
}

// 64-lane sum via DPP (row_shr 1/2/4/8 + row_bcast 15/31). Total lands in
// lane 63. bound_ctrl=true -> invalid source lanes contribute 0.
#define DPP_ADD(v, ctrl)                                                     \
    do {                                                                     \
        float _t = __builtin_bit_cast(                                       \
            float, __builtin_amdgcn_update_dpp(                              \
                       0, __builtin_bit_cast(int, v), ctrl, 0xf, 0xf, true));\
        (v) += _t;                                                           \
    } while (0)

__device__ __forceinline__ float dpp_sum64(float v) {
    DPP_ADD(v, 0x111);  // row_shr:1
    DPP_ADD(v, 0x112);  // row_shr:2
    DPP_ADD(v, 0x114);  // row_shr:4
    DPP_ADD(v, 0x118);  // row_shr:8
    DPP_ADD(v, 0x142);  // row_bcast:15
    DPP_ADD(v, 0x143);  // row_bcast:31
    return v;           // lane 63 holds the wave total
}

// ---------------------------------------------------------------------------
// Detect int64 vs int32 edge_index (int64 little-endian high words are 0).
// ---------------------------------------------------------------------------
__global__ void detect_kernel(const unsigned int* __restrict__ ei,
                              unsigned int* __restrict__ flag) {
    if (threadIdx.x == 0 && blockIdx.x == 0) {
        unsigned int v = 0;
        for (int i = 1; i < 256; i += 2) v |= ei[i];
        *flag = (v == 0u) ? 1u : 0u;
    }
}

// ---------------------------------------------------------------------------
// Phase 1 (fused): A = x @ w1[0:128,:], B = x @ w1[128:256,:] in ONE block.
// x-tile (16x128) staged to LDS once; thread = one column of BOTH halves.
// Inner loop: per 4-k chunk, 16x ds_read_b128 (uniform, broadcast) + 128 fma.
// ---------------------------------------------------------------------------
__global__ void __launch_bounds__(256) node_gemm_fused(
    const float* __restrict__ x, const float* __restrict__ w1,
    __half* __restrict__ AB, int num_nodes) {
    __shared__ float xs[16][GNN_IN];
    const int tid = threadIdx.x;
    const int r0  = blockIdx.x * 16;

    for (int i = tid; i < 16 * GNN_IN / 4; i += 256) {
        const int rr = i >> 5;
        const int cc = (i & 31) << 2;
        const int r = min(r0 + rr, num_nodes - 1);
        *(float4*)&xs[rr][cc] = *(const float4*)(x + (size_t)r * GNN_IN + cc);
    }
    __syncthreads();

    float accA[16], accB[16];
#pragma unroll
    for (int r = 0; r < 16; ++r) { accA[r] = 0.f; accB[r] = 0.f; }

    const float* __restrict__ wA = w1 + tid;
    const float* __restrict__ wB = w1 + (size_t)GNN_IN * HID + tid;

    for (int k0 = 0; k0 < GNN_IN; k0 += 4) {
        float wa[4], wb[4];
#pragma unroll
        for (int kk = 0; kk < 4; ++kk) {
            wa[kk] = wA[(size_t)(k0 + kk) * HID];
            wb[kk] = wB[(size_t)(k0 + kk) * HID];
        }
#pragma unroll
        for (int r = 0; r < 16; ++r) {
            const float4 xv = *(const float4*)&xs[r][k0];
            accA[r] = fmaf(xv.x, wa[0], accA[r]);
            accA[r] = fmaf(xv.y, wa[1], accA[r]);
            accA[r] = fmaf(xv.z, wa[2], accA[r]);
            accA[r] = fmaf(xv.w, wa[3], accA[r]);
            accB[r] = fmaf(xv.x, wb[0], accB[r]);
            accB[r] = fmaf(xv.y, wb[1], accB[r]);
            accB[r] = fmaf(xv.z, wb[2], accB[r]);
            accB[r] = fmaf(xv.w, wb[3], accB[r]);
        }
    }

    __half* oA = AB + tid;
    __half* oB = AB + (size_t)num_nodes * HID + tid;
#pragma unroll
    for (int r = 0; r < 16; ++r) {
        if (r0 + r < num_nodes) {
            oA[(size_t)(r0 + r) * HID] = __float2half_rn(accA[r]);
            oB[(size_t)(r0 + r) * HID] = __float2half_rn(accB[r]);
        }
    }
}

// ---------------------------------------------------------------------------
// Phase 2: wave per edge, 4 edges/iter. Scalar index/ed loads (uniform),
// SGPR-base gathers, packed fp16 h-math + dot2, DPP reduce (no LDS pipe).
// ---------------------------------------------------------------------------
__global__ void __launch_bounds__(256) edge_kernel_fp16(
    const __half* __restrict__ A, const __half* __restrict__ B,
    const void* __restrict__ ei, const float* __restrict__ ed,
    const float* __restrict__ w1, const float* __restrict__ b1,
    const float* __restrict__ w2, const float* __restrict__ b2,
    const unsigned int* __restrict__ flag,
    float* __restrict__ out, int num_edges) {
    const int lane   = threadIdx.x & 63;
    const int wave   = (blockIdx.x * blockDim.x + threadIdx.x) >> 6;
    const int nwaves = (gridDim.x * blockDim.x) >> 6;
    const int c0     = lane << 2;  // 4 columns per lane

    const float4 b1v = *(const float4*)(b1 + c0);
    float wt[4][4];
#pragma unroll
    for (int k = 0; k < 4; ++k)
        *(float4*)wt[k] = *(const float4*)(w1 + (size_t)(2 * GNN_IN + k) * HID + c0);
    const float4 w2f = *(const float4*)(w2 + c0);
    const f16x2  w2A = pkcvt(w2f.x, w2f.y);
    const f16x2  w2B = pkcvt(w2f.z, w2f.w);
    const float  b2v = b2[0];
    const int   is64 = __builtin_amdgcn_readfirstlane((int)(*flag));
    const f16x2 zero = {(_Float16)0.f, (_Float16)0.f};

    // chunk rounded to multiple of 4 so es (and float4 stores) stay aligned
    const int chunk = (((num_edges + nwaves - 1) / nwaves) + 3) & ~3;
    const int e0s = __builtin_amdgcn_readfirstlane(wave * chunk);
    const int e1s = __builtin_amdgcn_readfirstlane(min(num_edges, e0s + chunk));

    for (int es = e0s; es < e1s; es += 4) {
        int eid[4];
#pragma unroll
        for (int j = 0; j < 4; ++j) eid[j] = min(es + j, e1s - 1);

        int rr[4], cc[4];
        if (is64) {
#pragma unroll
            for (int j = 0; j < 4; ++j) {
                const int4 v = *(const int4*)((const char*)ei + (size_t)eid[j] * 16);
                rr[j] = v.x; cc[j] = v.z;
            }
        } else {
#pragma unroll
            for (int j = 0; j < 4; ++j) {
                const int2 v = *(const int2*)((const char*)ei + (size_t)eid[j] * 8);
                rr[j] = v.x; cc[j] = v.y;
            }
        }

        h4v av[4], bv[4];
        float4 edv[4];
#pragma unroll
        for (int j = 0; j < 4; ++j) {
            av[j]  = *(const h4v*)(A + (size_t)rr[j] * HID + c0);
            bv[j]  = *(const h4v*)(B + (size_t)cc[j] * HID + c0);
            edv[j] = *(const float4*)(ed + (size_t)eid[j] * 4);
        }

        float p[4];
#pragma unroll
        for (int j = 0; j < 4; ++j) {
            float c_[4] = {b1v.x, b1v.y, b1v.z, b1v.w};
            const float ep[4] = {edv[j].x, edv[j].y, edv[j].z, edv[j].w};
#pragma unroll
            for (int k = 0; k < 4; ++k)
#pragma unroll
                for (int q = 0; q < 4; ++q) c_[q] = fmaf(ep[k], wt[k][q], c_[q]);
            f16x2 h0 = (av[j].a + bv[j].a) + pkcvt(c_[0], c_[1]);
            f16x2 h1 = (av[j].b + bv[j].b) + pkcvt(c_[2], c_[3]);
            h0 = __builtin_elementwise_max(h0, zero);
            h1 = __builtin_elementwise_max(h1, zero);
            p[j] = fdot2f(h0, w2A, fdot2f(h1, w2B, 0.f));
        }

#pragma unroll
        for (int j = 0; j < 4; ++j) p[j] = dpp_sum64(p[j]);

        float s[4];
#pragma unroll
        for (int j = 0; j < 4; ++j) s[j] = 1.f / (1.f + __expf(-(p[j] + b2v)));

        if (lane == 63) {
            if (es + 3 < e1s) {
                *(float4*)(out + es) = make_float4(s[0], s[1], s[2], s[3]);
            } else {
#pragma unroll
                for (int j = 0; j < 4; ++j)
                    if (es + j < e1s) out[es + j] = s[j];
            }
        }
    }
}

// ---------------------------------------------------------------------------
// Fallback (ws too small): direct per-edge computation, fp32.
// ---------------------------------------------------------------------------
__global__ void __launch_bounds__(256) edge_direct_kernel(
    const float* __restrict__ x, const void* __restrict__ ei,
    const float* __restrict__ ed, const float* __restrict__ w1,
    const float* __restrict__ b1, const float* __restrict__ w2,
    const float* __restrict__ b2, const unsigned int* __restrict__ flag,
    float* __restrict__ out, int num_edges, int num_nodes) {
    const int lane   = threadIdx.x & 63;
    const int wave   = (blockIdx.x * blockDim.x + threadIdx.x) >> 6;
    const int nwaves = (gridDim.x * blockDim.x) >> 6;
    const int c0     = lane << 2;

    const float4 w2v = *(const float4*)(w2 + c0);
    const float4 b1v = *(const float4*)(b1 + c0);
    float wt[4][4];
#pragma unroll
    for (int k = 0; k < 4; ++k)
        *(float4*)wt[k] = *(const float4*)(w1 + (size_t)(2 * GNN_IN + k) * HID + c0);
    const float b2v  = b2[0];
    const int   is64 = flag ? (int)(*flag) : 0;

    const float* w2p = (const float*)&w2v;
    const float* b1p = (const float*)&b1v;

    const int chunk = (num_edges + nwaves - 1) / nwaves;
    const int e0 = wave * chunk;
    const int e1 = min(num_edges, e0 + chunk);

    for (int e = e0; e < e1; ++e) {
        int row, col;
        if (is64) {
            const int4 v = ((const int4*)ei)[e];
            row = v.x; col = v.z;
        } else {
            const int2 v = ((const int2*)ei)[e];
            row = v.x; col = v.y;
        }
        row = min(max(row, 0), num_nodes - 1);
        col = min(max(col, 0), num_nodes - 1);

        const float4 edv = *(const float4*)(ed + (size_t)e * 4);
        const float* edp = (const float*)&edv;

        float h4[4];
#pragma unroll
        for (int jj = 0; jj < 4; ++jj) {
            float h = b1p[jj];
#pragma unroll
            for (int k = 0; k < 4; ++k) h = fmaf(edp[k], wt[k][jj], h);
            h4[jj] = h;
        }
        const float* xr = x + (size_t)row * GNN_IN;
        const float* xc = x + (size_t)col * GNN_IN;
        for (int k = 0; k < GNN_IN; ++k) {
            const float xv = xr[k];
            const float4 wv = *(const float4*)(w1 + (size_t)k * HID + c0);
            h4[0] = fmaf(xv, wv.x, h4[0]); h4[1] = fmaf(xv, wv.y, h4[1]);
            h4[2] = fmaf(xv, wv.z, h4[2]); h4[3] = fmaf(xv, wv.w, h4[3]);
        }
        for (int k = 0; k < GNN_IN; ++k) {
            const float xv = xc[k];
            const float4 wv = *(const float4*)(w1 + (size_t)(GNN_IN + k) * HID + c0);
            h4[0] = fmaf(xv, wv.x, h4[0]); h4[1] = fmaf(xv, wv.y, h4[1]);
            h4[2] = fmaf(xv, wv.z, h4[2]); h4[3] = fmaf(xv, wv.w, h4[3]);
        }
        float p = 0.f;
#pragma unroll
        for (int jj = 0; jj < 4; ++jj) {
            const float h = fmaxf(h4[jj], 0.f);
            p = fmaf(h, w2p[jj], p);
        }
#pragma unroll
        for (int off = 32; off >= 1; off >>= 1) p += __shfl_xor(p, off, 64);
        if (lane == 0) out[e] = 1.f / (1.f + __expf(-(p + b2v)));
    }
}

extern "C" void kernel_launch(void* const* d_in, const int* in_sizes, int n_in,
                              void* d_out, int out_size, void* d_ws, size_t ws_size,
                              hipStream_t stream) {
    const float* x  = (const float*)d_in[0];
    const void*  ei = d_in[1];
    const float* ed = (const float*)d_in[2];
    const float* w1 = (const float*)d_in[3];
    const float* b1 = (const float*)d_in[4];
    const float* w2 = (const float*)d_in[5];
    const float* b2 = (const float*)d_in[6];
    float* out = (float*)d_out;

    const int num_nodes = in_sizes[0] / GNN_IN;  // 10000
    const int num_edges = in_sizes[1] / 2;       // 640000

    unsigned int* flag = nullptr;
    if (ws_size >= 16) {
        flag = (unsigned int*)d_ws;
        detect_kernel<<<1, 64, 0, stream>>>((const unsigned int*)ei, flag);
    }

    const size_t need = 256 + (size_t)2 * num_nodes * HID * sizeof(__half);
    if (flag && ws_size >= need) {
        __half* A = (__half*)((char*)d_ws + 256);
        node_gemm_fused<<<(num_nodes + 15) / 16, 256, 0, stream>>>(
            x, w1, A, num_nodes);
        __half* Bp = A + (size_t)num_nodes * HID;
        edge_kernel_fp16<<<2048, 256, 0, stream>>>(A, Bp, ei, ed, w1, b1, w2, b2,
                                                   flag, out, num_edges);
    } else {
        edge_direct_kernel<<<4096, 256, 0, stream>>>(x, ei, ed, w1, b1, w2, b2,
                                                     flag, out, num_edges, num_nodes);
    }
}